// Round 2
// baseline (300.554 us; speedup 1.0000x reference)
//
#include <hip/hip_runtime.h>

#define TT 128
#define BB 512
#define DD 500
#define NVOCAB 1000
#define NV4 125   // DD floats = 125 float4 per row (2000 B, 16B-aligned)

// ---------------------------------------------------------------------------
// Workspace layout (ws 16B-aligned):
//   mask    : ulonglong2[BB]        (16 B/col, 128-bit valid mask)     8 KB
//   lohi    : unsigned short[TT*BB] (lo | hi<<7 per segment)           128 KB
//   new_len : int[BB]                                                  2 KB
//   ord     : int[BB]               (sorted column order)              2 KB
//   slen    : int[BB]               (sorted lengths, int)              2 KB
//   desc    : int[TT*BB]            (per-output-row descriptor)        256 KB
// ---------------------------------------------------------------------------

// Kernel 1: per-column greedy packer metadata. 8 blocks x 64 threads.
__global__ void __launch_bounds__(64)
meta_kernel(const int* __restrict__ src,
            const int* __restrict__ token_lengths,
            const int* __restrict__ token_len_p,
            unsigned short* __restrict__ lohi,
            int* __restrict__ new_len,
            ulonglong2* __restrict__ mask) {
    __shared__ int tl[NVOCAB];
    __shared__ int ssrc[TT * 64];

    int tid = threadIdx.x;
    for (int i = tid; i < NVOCAB; i += 64) tl[i] = token_lengths[i];

    int b = blockIdx.x * 64 + tid;
    #pragma unroll 8
    for (int t = 0; t < TT; ++t) ssrc[t * 64 + tid] = src[t * BB + b];
    __syncthreads();

    // token_len arrives as a 1-element int array; guard vs f32 bits.
    int bits = token_len_p[0];
    int token_len = bits;
    if (bits > 1000000 || bits <= 0) token_len = (int)__int_as_float(bits);

    int curr = 0, seg = 0, lo = 0, pend = -1;
    unsigned long long m0 = 0ull, m1 = 0ull;
    for (int t = 0; t < TT; ++t) {
        int s = ssrc[t * 64 + tid];
        if (s == 1) continue;                  // pad: invalid
        int l = (s == 0) ? 4 : tl[s];
        if (pend >= 0 && curr + l > token_len) {
            lohi[seg * BB + b] = (unsigned short)(lo | (pend << 7));
            lo = pend + 1; curr = 0; seg++;
        }
        curr += l; pend = t;
        if (t < 64) m0 |= 1ull << t; else m1 |= 1ull << (t - 64);
    }
    if (pend >= 0) {                           // final segment (nxt==BIG)
        lohi[seg * BB + b] = (unsigned short)(lo | (pend << 7));
        seg++;
    }
    new_len[b] = seg;
    mask[b] = make_ulonglong2(m0, m1);
}

// Kernel 2: stable descending argsort (rank-count). One block, LDS broadcasts.
__global__ void __launch_bounds__(BB)
sort_kernel(const int* __restrict__ new_len,
            int* __restrict__ ord,
            int* __restrict__ slen,
            float* __restrict__ out_len) {
    __shared__ int lens[BB];
    __shared__ int sord[BB];
    int j = threadIdx.x;
    lens[j] = new_len[j];
    __syncthreads();
    int lj = lens[j];
    int rank = 0;
    #pragma unroll 8
    for (int i = 0; i < BB; ++i) {
        int li = lens[i];
        rank += (int)((li > lj) || (li == lj && i < j));
    }
    sord[rank] = j;
    __syncthreads();
    int b = sord[j];
    int n = lens[b];
    ord[j]  = b;
    slen[j] = n;
    out_len[j] = (float)n;
}

// Kernel 3: grid-parallel descriptor build (the round-0 version of this was a
// single block on one CU; at 128x512 threads it's a few µs).
// desc = b | lo<<9 | hi<<16 | force<<23. Identity rows become 1-element
// segments [r,r] with force-weight=1, unifying the gather code path.
__global__ void __launch_bounds__(BB)
desc_kernel(const int* __restrict__ ord, const int* __restrict__ slen,
            const unsigned short* __restrict__ lohi, int* __restrict__ desc) {
    int r = blockIdx.x, j = threadIdx.x;
    int b = ord[j];
    int n = slen[j];
    int d;
    if (r < n) {
        int lh = (int)lohi[r * BB + b];
        d = b | ((lh & 127) << 9) | (((lh >> 7) & 127) << 16);
    } else {
        d = b | (r << 9) | (r << 16) | (1 << 23);
    }
    desc[r * BB + j] = d;   // coalesced
}

// ---------------------------------------------------------------------------
// Kernel 4: gather. 256 threads = 2 half-blocks x 4 output rows each.
// All 4 desc loads, then all 4 first emb loads + 4 mask loads issue
// back-to-back (8 independent requests in flight per wave) before any
// dependent use; packed-segment tails run with 2 outstanding loads (unroll-2).
// This attacks the measured ~7000-cycle effective latency (MLP-bound).
// ---------------------------------------------------------------------------
__device__ __forceinline__ float maskw(ulonglong2 m, int t, int f) {
    unsigned long long word = (t < 64) ? m.x : m.y;
    float bit = (float)((word >> (t & 63)) & 1ull);
    return f ? 1.0f : bit;
}

__global__ void __launch_bounds__(256)
gather_kernel(const float* __restrict__ emb,
              const int* __restrict__ desc,
              const ulonglong2* __restrict__ mask,
              float* __restrict__ out) {
    int half = threadIdx.x >> 7;
    int lane = threadIdx.x & 127;
    if (lane >= NV4) return;
    int base = blockIdx.x * 8 + half * 4;   // 4 consecutive output rows

#define EMB4(b, t) (((const float4*)(emb + ((size_t)(t) * BB + (b)) * DD))[lane])

    // 4 independent (wave-uniform) descriptor loads
    int d0 = desc[base + 0];
    int d1 = desc[base + 1];
    int d2 = desc[base + 2];
    int d3 = desc[base + 3];

    int b0 = d0 & 511, lo0 = (d0 >> 9) & 127, hi0 = (d0 >> 16) & 127, f0 = (d0 >> 23) & 1;
    int b1 = d1 & 511, lo1 = (d1 >> 9) & 127, hi1 = (d1 >> 16) & 127, f1 = (d1 >> 23) & 1;
    int b2 = d2 & 511, lo2 = (d2 >> 9) & 127, hi2 = (d2 >> 16) & 127, f2 = (d2 >> 23) & 1;
    int b3 = d3 & 511, lo3 = (d3 >> 9) & 127, hi3 = (d3 >> 16) & 127, f3 = (d3 >> 23) & 1;

    // 4 first-loads + 4 mask loads, all independent -> 8 outstanding
    float4 v0 = EMB4(b0, lo0);
    float4 v1 = EMB4(b1, lo1);
    float4 v2 = EMB4(b2, lo2);
    float4 v3 = EMB4(b3, lo3);
    ulonglong2 m0 = mask[b0];
    ulonglong2 m1 = mask[b1];
    ulonglong2 m2 = mask[b2];
    ulonglong2 m3 = mask[b3];

#define ROW(K)                                                                 \
    {                                                                          \
        float w = maskw(m##K, lo##K, f##K);                                    \
        float4 a;                                                              \
        a.x = w * v##K.x; a.y = w * v##K.y; a.z = w * v##K.z; a.w = w * v##K.w;\
        int t = lo##K + 1;                                                     \
        for (; t + 1 <= hi##K; t += 2) {                                       \
            float4 x = EMB4(b##K, t);                                          \
            float4 y = EMB4(b##K, t + 1);                                      \
            float wx = maskw(m##K, t, 0);                                      \
            float wy = maskw(m##K, t + 1, 0);                                  \
            a.x = fmaf(wx, x.x, a.x); a.y = fmaf(wx, x.y, a.y);                \
            a.z = fmaf(wx, x.z, a.z); a.w = fmaf(wx, x.w, a.w);                \
            a.x = fmaf(wy, y.x, a.x); a.y = fmaf(wy, y.y, a.y);                \
            a.z = fmaf(wy, y.z, a.z); a.w = fmaf(wy, y.w, a.w);                \
        }                                                                      \
        if (t <= hi##K) {                                                      \
            float4 x = EMB4(b##K, t);                                          \
            float wx = maskw(m##K, t, 0);                                      \
            a.x = fmaf(wx, x.x, a.x); a.y = fmaf(wx, x.y, a.y);                \
            a.z = fmaf(wx, x.z, a.z); a.w = fmaf(wx, x.w, a.w);                \
        }                                                                      \
        ((float4*)(out + (size_t)(base + K) * DD))[lane] = a;                  \
    }

    ROW(0)
    ROW(1)
    ROW(2)
    ROW(3)

#undef ROW
#undef EMB4
}

extern "C" void kernel_launch(void* const* d_in, const int* in_sizes, int n_in,
                              void* d_out, int out_size, void* d_ws, size_t ws_size,
                              hipStream_t stream) {
    const float* embedded      = (const float*)d_in[0];
    const int*   src           = (const int*)d_in[1];
    // d_in[2] = lengths (unused by reference computation)
    const int*   token_lengths = (const int*)d_in[3];
    const int*   token_len_p   = (const int*)d_in[4];

    float* out = (float*)d_out;                 // T*B*D packed rows + B lengths

    ulonglong2*     mask    = (ulonglong2*)d_ws;                    // 8 KB
    unsigned short* lohi    = (unsigned short*)(mask + BB);         // 128 KB
    int*            new_len = (int*)(lohi + TT * BB);               // 2 KB
    int*            ord     = new_len + BB;                         // 2 KB
    int*            slen    = ord + BB;                             // 2 KB
    int*            desc    = slen + BB;                            // 256 KB

    meta_kernel<<<BB / 64, 64, 0, stream>>>(src, token_lengths, token_len_p,
                                            lohi, new_len, mask);
    sort_kernel<<<1, BB, 0, stream>>>(new_len, ord, slen,
                                      out + (size_t)TT * BB * DD);
    desc_kernel<<<TT, BB, 0, stream>>>(ord, slen, lohi, desc);
    gather_kernel<<<TT * BB / 8, 256, 0, stream>>>(embedded, desc, mask, out);
}

// Round 4
// 291.890 us; speedup vs baseline: 1.0297x; 1.0297x over previous
//
#include <hip/hip_runtime.h>

#define TT 128
#define BB 512
#define DD 500
#define NVOCAB 1000
#define NV4 125   // DD floats = 125 float4 per row (2000 B, 16B-aligned)

// ---------------------------------------------------------------------------
// Workspace layout (ws 16B-aligned) — kept <= the ~396 KB footprint proven in
// rounds 0-2 (round 3's 652 KB uint2-desc build is the prime suspect for the
// container fault):
//   mask    : ulonglong2[BB]   (128-bit valid mask per column)        8 KB
//   lohi    : ushort[TT*BB]    (lo | hi<<7 per segment)             128 KB
//   ord     : int[BB]          (sorted column order)                  2 KB
//   slen    : int[BB]          (sorted lengths)                       2 KB
//   desc    : int[TT*BB]       (per-output-row descriptor)          256 KB
// ---------------------------------------------------------------------------

// Kernel 1: fused metadata + sort. ONE block, 512 threads (1 thread/column).
// Batch-16 coalesced src reads keep ~16 loads in flight per thread; then the
// O(B^2) stable rank-count sort runs in the same block (LDS broadcasts).
__global__ void __launch_bounds__(512)
meta_sort_kernel(const int* __restrict__ src,
                 const int* __restrict__ token_lengths,
                 const int* __restrict__ token_len_p,
                 unsigned short* __restrict__ lohi,
                 ulonglong2* __restrict__ mask,
                 int* __restrict__ ord,
                 int* __restrict__ slen,
                 float* __restrict__ out_len) {
    __shared__ int tl[NVOCAB];
    __shared__ int lens[BB];
    __shared__ int sord[BB];
    int b = threadIdx.x;
    for (int i = b; i < NVOCAB; i += 512) tl[i] = token_lengths[i];
    __syncthreads();

    // token_len arrives as a 1-element int array; guard vs f32 bits.
    int bits = token_len_p[0];
    int token_len = bits;
    if (bits > 1000000 || bits <= 0) token_len = (int)__int_as_float(bits);

    int curr = 0, seg = 0, lo = 0, pend = -1;
    unsigned long long m0 = 0ull, m1 = 0ull;
    for (int t0 = 0; t0 < TT; t0 += 16) {
        int s_arr[16];
        #pragma unroll
        for (int k = 0; k < 16; ++k) s_arr[k] = src[(t0 + k) * BB + b];
        #pragma unroll
        for (int k = 0; k < 16; ++k) {
            int t = t0 + k;
            int s = s_arr[k];
            if (s == 1) continue;              // pad: invalid
            int l = (s == 0) ? 4 : tl[s];
            if (pend >= 0 && curr + l > token_len) {
                lohi[seg * BB + b] = (unsigned short)(lo | (pend << 7));
                lo = pend + 1; curr = 0; seg++;
            }
            curr += l; pend = t;
            if (t < 64) m0 |= 1ull << t; else m1 |= 1ull << (t - 64);
        }
    }
    if (pend >= 0) {                           // final segment (nxt==BIG)
        lohi[seg * BB + b] = (unsigned short)(lo | (pend << 7));
        seg++;
    }
    mask[b] = make_ulonglong2(m0, m1);
    lens[b] = seg;
    __syncthreads();

    // stable descending rank-count sort (thread b doubles as output slot j)
    int lj = lens[b];
    int rank = 0;
    #pragma unroll 8
    for (int i = 0; i < BB; ++i) {
        int li = lens[i];
        rank += (int)((li > lj) || (li == lj && i < b));
    }
    sord[rank] = b;
    __syncthreads();
    int bb = sord[b];
    int n  = lens[bb];
    ord[b]  = bb;
    slen[b] = n;
    out_len[b] = (float)n;
}

// Kernel 2: grid-parallel descriptor build (128 blocks x 512 threads, ~3 us).
// desc = b | lo<<9 | hi<<16 | force<<23. Identity rows r>=n become 1-element
// segments [r,r] with force-weight=1, unifying the gather code path.
__global__ void __launch_bounds__(BB)
desc_kernel(const int* __restrict__ ord, const int* __restrict__ slen,
            const unsigned short* __restrict__ lohi, int* __restrict__ desc) {
    int r = blockIdx.x, j = threadIdx.x;
    int b = ord[j];
    int n = slen[j];
    int d;
    if (r < n) {
        int lh = (int)lohi[r * BB + b];
        d = b | ((lh & 127) << 9) | (((lh >> 7) & 127) << 16);
    } else {
        d = b | (r << 9) | (r << 16) | (1 << 23);
    }
    desc[r * BB + j] = d;           // coalesced
}

// ---------------------------------------------------------------------------
// Kernel 3: gather. ONE WAVE PER OUTPUT ROW (64 lanes own float4 `lane` and
// `lane+64`). Segment loop loads batches of 4 t-steps into statically-indexed
// arrays BEFORE any use -> 8 independent 1 KB loads in flight per wave
// (round 2's attempt was provably sunk by the compiler: VGPR_Count stayed 32).
// mask[b] is a wave-uniform 16 B load off the critical path (emb loads depend
// only on desc). FMA accumulation preserves ascending-t order => bit-exact.
// ---------------------------------------------------------------------------
__global__ void __launch_bounds__(256)
gather_kernel(const float* __restrict__ emb,
              const int* __restrict__ desc,
              const ulonglong2* __restrict__ mask,
              float* __restrict__ out) {
    int idx  = blockIdx.x * 4 + (threadIdx.x >> 6);   // output row r*BB+j
    int lane = threadIdx.x & 63;
    int d = desc[idx];                                 // wave-uniform, 1 txn
    int b     = d & 511;
    int lo    = (d >> 9) & 127;
    int hi    = (d >> 16) & 127;
    int force = (d >> 23) & 1;
    ulonglong2 m = mask[b];                            // uniform, parallel w/ emb

    int  q1   = lane + 64;
    bool has2 = q1 < NV4;                              // lanes 0..60

    float4 a0 = make_float4(0.f, 0.f, 0.f, 0.f);
    float4 a1 = make_float4(0.f, 0.f, 0.f, 0.f);

#define WGT(T) (force ? 1.0f : \
    (float)((((T) < 64 ? (m.x >> (T)) : (m.y >> ((T) - 64)))) & 1ull))
#define FMA4(A, W, X) { A.x = fmaf(W, X.x, A.x); A.y = fmaf(W, X.y, A.y); \
                        A.z = fmaf(W, X.z, A.z); A.w = fmaf(W, X.w, A.w); }

    int t = lo;
    for (; t + 3 <= hi; t += 4) {                      // batch-4: 8 loads deep
        float4 x0[4], x1[4];
        #pragma unroll
        for (int k = 0; k < 4; ++k) {
            const float4* row = (const float4*)(emb + ((size_t)(t + k) * BB + b) * DD);
            x0[k] = row[lane];
            x1[k] = has2 ? row[q1] : make_float4(0.f, 0.f, 0.f, 0.f);
        }
        #pragma unroll
        for (int k = 0; k < 4; ++k) {                  // t-order preserved
            float w = WGT(t + k);
            FMA4(a0, w, x0[k])
            FMA4(a1, w, x1[k])
        }
    }
    for (; t <= hi; ++t) {                             // tail (identity: 1 iter)
        const float4* row = (const float4*)(emb + ((size_t)t * BB + b) * DD);
        float4 x0 = row[lane];
        float4 x1 = has2 ? row[q1] : make_float4(0.f, 0.f, 0.f, 0.f);
        float w = WGT(t);
        FMA4(a0, w, x0)
        FMA4(a1, w, x1)
    }

    float4* orow = (float4*)(out + (size_t)idx * DD);
    orow[lane] = a0;
    if (has2) orow[q1] = a1;
#undef WGT
#undef FMA4
}

extern "C" void kernel_launch(void* const* d_in, const int* in_sizes, int n_in,
                              void* d_out, int out_size, void* d_ws, size_t ws_size,
                              hipStream_t stream) {
    const float* embedded      = (const float*)d_in[0];
    const int*   src           = (const int*)d_in[1];
    // d_in[2] = lengths (unused by reference computation)
    const int*   token_lengths = (const int*)d_in[3];
    const int*   token_len_p   = (const int*)d_in[4];

    float* out = (float*)d_out;                 // T*B*D packed rows + B lengths

    ulonglong2*     mask = (ulonglong2*)d_ws;                       // 8 KB
    unsigned short* lohi = (unsigned short*)(mask + BB);            // 128 KB
    int*            ord  = (int*)(lohi + TT * BB);                  // 2 KB
    int*            slen = ord + BB;                                // 2 KB
    int*            desc = slen + BB;                               // 256 KB

    meta_sort_kernel<<<1, BB, 0, stream>>>(src, token_lengths, token_len_p,
                                           lohi, mask, ord, slen,
                                           out + (size_t)TT * BB * DD);
    desc_kernel<<<TT, BB, 0, stream>>>(ord, slen, lohi, desc);
    gather_kernel<<<TT * BB / 4, 256, 0, stream>>>(embedded, desc, mask, out);
}